// Round 1
// 1331.047 us; speedup vs baseline: 1.0042x; 1.0042x over previous
//
#include <hip/hip_runtime.h>
#include <stdint.h>

// Problem constants
#define BB 2
#define SS 2048
#define DD 1024
#define HH 16
#define DKV 64
#define BH (BB*HH)          // 32
#define MROWS (BB*SS)       // 4096

typedef __attribute__((ext_vector_type(8))) short bf16x8;
typedef __attribute__((ext_vector_type(4))) float f32x4;

#define MFMA16 __builtin_amdgcn_mfma_f32_16x16x32_bf16

__device__ inline short f2bf(float x) {
    union { float f; unsigned u; } v; v.f = x;
    unsigned r = (v.u + 0x7FFFu + ((v.u >> 16) & 1u)) >> 16;
    return (short)r;
}
__device__ inline float bf2f(short h) {
    union { unsigned u; float f; } v; v.u = ((unsigned)(unsigned short)h) << 16;
    return v.f;
}

// Async global->LDS, 16B per lane. LDS dest = wave-uniform base + lane*16.
__device__ inline void gload_lds16(const short* g, short* l) {
    __builtin_amdgcn_global_load_lds(
        (const __attribute__((address_space(1))) void*)g,
        (__attribute__((address_space(3))) void*)l, 16, 0, 0);
}

// ---------------------------------------------------------------------------
// Cast hidden_states fp32 -> split bf16 (hi + lo)
// ---------------------------------------------------------------------------
__global__ __launch_bounds__(256) void cast_split_kernel(
    const float* __restrict__ src, short* __restrict__ hi, short* __restrict__ lo, int n)
{
    int i = (blockIdx.x * 256 + threadIdx.x) * 4;
    if (i >= n) return;
    float4 v = *(const float4*)(src + i);
    short h0 = f2bf(v.x), h1 = f2bf(v.y), h2 = f2bf(v.z), h3 = f2bf(v.w);
    short l0 = f2bf(v.x - bf2f(h0)), l1 = f2bf(v.y - bf2f(h1));
    short l2 = f2bf(v.z - bf2f(h2)), l3 = f2bf(v.w - bf2f(h3));
    *(short4*)(hi + i) = make_short4(h0, h1, h2, h3);
    *(short4*)(lo + i) = make_short4(l0, l1, l2, l3);
}

// ---------------------------------------------------------------------------
// Transpose 1024x1024 fp32 W -> bf16 W^T (optionally split hi/lo)
// ---------------------------------------------------------------------------
__global__ void transpose_split_kernel(
    const float* __restrict__ src, short* __restrict__ hi, short* __restrict__ lo, int with_lo)
{
    __shared__ float tile[32][33];
    int bx = blockIdx.x * 32, by = blockIdx.y * 32;
    int tx = threadIdx.x, ty = threadIdx.y;
    for (int i = ty; i < 32; i += 8)
        tile[i][tx] = src[(size_t)(by + i) * DD + bx + tx];
    __syncthreads();
    for (int i = ty; i < 32; i += 8) {
        float v = tile[tx][i];
        short h = f2bf(v);
        size_t off = (size_t)(bx + i) * DD + by + tx;
        hi[off] = h;
        if (with_lo) lo[off] = f2bf(v - bf2f(h));
    }
}

// ---------------------------------------------------------------------------
// Relative-position bias table
// ---------------------------------------------------------------------------
__global__ __launch_bounds__(256) void bias_table_kernel(
    const float* __restrict__ rel_bias, float* __restrict__ btab)
{
    int t = blockIdx.x * 256 + threadIdx.x;
    if (t >= HH * 4096) return;
    int h = t >> 12, idx = t & 4095;
    int delta = idx - 2048;          // k - q
    int n = -delta;                  // q - k
    int ret = 0;
    if (n < 0) { ret = 16; n = -n; }
    int bucket;
    if (n < 8) bucket = ret + n;
    else {
        int m = 0;
        m += (n >= 12); m += (n >= 16); m += (n >= 23); m += (n >= 32);
        m += (n >= 46); m += (n >= 64); m += (n >= 91); m += (n >= 128);
        int val = 8 + m; if (val > 15) val = 15;
        bucket = ret + val;
    }
    btab[t] = rel_bias[bucket * HH + h];
}

// ---------------------------------------------------------------------------
// Split-precision GEMM for Q,K projections. Staging via global_load_lds:
// wave w stages buffer w (8 KB, 8 chunks of 64 lanes x 16B, linear layout).
// ---------------------------------------------------------------------------
__global__ __launch_bounds__(256) void gemm_split_qk_kernel(
    const short* __restrict__ Ah, const short* __restrict__ Al,
    const short* __restrict__ Bh, const short* __restrict__ Bl,
    short* __restrict__ Qh, short* __restrict__ Ql,
    short* __restrict__ Kh, short* __restrict__ Kl)
{
    __shared__ short sAh[128*32], sAl[128*32], sBh[128*32], sBl[128*32];
    int tid = threadIdx.x;
    int w = tid >> 6, lane = tid & 63, col = lane & 15, quad = lane >> 4;
    int wr = w >> 1, wc = w & 1;
    int bm0 = blockIdx.y * 128, bn0 = blockIdx.x * 128;

    const short* gsrc = (w == 0) ? Ah : (w == 1) ? Al : (w == 2) ? Bh : Bl;
    short* ldst = (w == 0) ? sAh : (w == 1) ? sAl : (w == 2) ? sBh : sBl;
    int rbase = (w < 2) ? bm0 : bn0;

    f32x4 acc[4][4];
#pragma unroll
    for (int i = 0; i < 4; ++i)
#pragma unroll
        for (int j = 0; j < 4; ++j) acc[i][j] = (f32x4){0.f,0.f,0.f,0.f};

    for (int k0 = 0; k0 < DD; k0 += 32) {
#pragma unroll
        for (int it = 0; it < 8; ++it) {
            int ci = it * 64 + lane;
            int row = ci >> 2, cg = (ci & 3) * 8;
            gload_lds16(gsrc + (size_t)(rbase + row) * DD + k0 + cg, ldst + it * 512);
        }
        __syncthreads();
        bf16x8 ah[4], al[4], bh[4], bl[4];
#pragma unroll
        for (int i = 0; i < 4; ++i) {
            int ra = (wr*64 + i*16 + col)*32 + quad*8;
            int rb = (wc*64 + i*16 + col)*32 + quad*8;
            ah[i] = *(bf16x8*)&sAh[ra];
            al[i] = *(bf16x8*)&sAl[ra];
            bh[i] = *(bf16x8*)&sBh[rb];
            bl[i] = *(bf16x8*)&sBl[rb];
        }
#pragma unroll
        for (int i = 0; i < 4; ++i)
#pragma unroll
            for (int j = 0; j < 4; ++j) {
                acc[i][j] = MFMA16(ah[i], bh[j], acc[i][j], 0, 0, 0);
                acc[i][j] = MFMA16(al[i], bh[j], acc[i][j], 0, 0, 0);
                acc[i][j] = MFMA16(ah[i], bl[j], acc[i][j], 0, 0, 0);
            }
        __syncthreads();
    }

#pragma unroll
    for (int i = 0; i < 4; ++i)
#pragma unroll
        for (int j = 0; j < 4; ++j)
#pragma unroll
            for (int r = 0; r < 4; ++r) {
                int gm = bm0 + wr*64 + i*16 + quad*4 + r;
                int gn = bn0 + wc*64 + j*16 + col;
                float v = acc[i][j][r];
                int b = gm >> 11, s = gm & 2047;
                int hh = (gn >> 6) & 15, d = gn & 63;
                size_t off = ((size_t)(b*HH + hh) * SS + s) * DKV + d;
                if (gn < 1024) {
                    v *= 0.125f;
                    short hv = f2bf(v);
                    Qh[off] = hv; Ql[off] = f2bf(v - bf2f(hv));
                } else {
                    short hv = f2bf(v);
                    Kh[off] = hv; Kl[off] = f2bf(v - bf2f(hv));
                }
            }
}

// ---------------------------------------------------------------------------
// Plain bf16 GEMM. Staging via global_load_lds: waves 0,1 -> sA halves,
// waves 2,3 -> sB halves.
// ---------------------------------------------------------------------------
__global__ __launch_bounds__(256) void gemm_plain_kernel(
    const short* __restrict__ A, const short* __restrict__ Bt,
    short* __restrict__ vt_out, float* __restrict__ f_out, int mode)
{
    __shared__ short sA[128*32], sB[128*32];
    int tid = threadIdx.x;
    int w = tid >> 6, lane = tid & 63, col = lane & 15, quad = lane >> 4;
    int wr = w >> 1, wc = w & 1;
    int bm0 = blockIdx.y * 128, bn0 = blockIdx.x * 128;

    int widx = w & 1;
    const short* gsrc = (w < 2) ? A : Bt;
    short* ldst = (w < 2) ? sA : sB;
    int rbase = (w < 2) ? bm0 : bn0;

    f32x4 acc[4][4];
#pragma unroll
    for (int i = 0; i < 4; ++i)
#pragma unroll
        for (int j = 0; j < 4; ++j) acc[i][j] = (f32x4){0.f,0.f,0.f,0.f};

    for (int k0 = 0; k0 < DD; k0 += 32) {
#pragma unroll
        for (int it = 0; it < 4; ++it) {
            int ci = (widx*4 + it) * 64 + lane;
            int row = ci >> 2, cg = (ci & 3) * 8;
            gload_lds16(gsrc + (size_t)(rbase + row) * DD + k0 + cg, ldst + (widx*4 + it) * 512);
        }
        __syncthreads();
        bf16x8 af[4], bf[4];
#pragma unroll
        for (int i = 0; i < 4; ++i) {
            af[i] = *(bf16x8*)&sA[(wr*64 + i*16 + col)*32 + quad*8];
            bf[i] = *(bf16x8*)&sB[(wc*64 + i*16 + col)*32 + quad*8];
        }
#pragma unroll
        for (int i = 0; i < 4; ++i)
#pragma unroll
            for (int j = 0; j < 4; ++j)
                acc[i][j] = MFMA16(af[i], bf[j], acc[i][j], 0, 0, 0);
        __syncthreads();
    }

#pragma unroll
    for (int i = 0; i < 4; ++i)
#pragma unroll
        for (int j = 0; j < 4; ++j)
#pragma unroll
            for (int r = 0; r < 4; ++r) {
                int gm = bm0 + wr*64 + i*16 + quad*4 + r;
                int gn = bn0 + wc*64 + j*16 + col;
                float v = acc[i][j][r];
                if (mode == 0) {
                    int b = gm >> 11, s = gm & 2047;
                    int hh = (gn >> 6) & 15, d = gn & 63;
                    vt_out[((size_t)(b*HH + hh) * DKV + d) * SS + s] = f2bf(v);
                } else {
                    f_out[(size_t)gm * DD + gn] = v;
                }
            }
}

// ---------------------------------------------------------------------------
// Fused attention (see header comments in the theory above).
// ---------------------------------------------------------------------------
__global__ __launch_bounds__(256, 4) void attn_kernel(
    const short* __restrict__ Qh, const short* __restrict__ Ql,
    const short* __restrict__ Kh, const short* __restrict__ Kl,
    const short* __restrict__ Vt, const float* __restrict__ btab_all,
    const int* __restrict__ mask, float* __restrict__ attn_out,
    short* __restrict__ ctx)
{
    __shared__ short Pt[4][16*64];   // per-WAVE P tile
    int qb = blockIdx.x * 64;
    int bh = blockIdx.y;
    int b = bh >> 4, h = bh & 15;
    int tid = threadIdx.x, w = tid >> 6, lane = tid & 63;
    int col = lane & 15, quad = lane >> 4;

    const short* Qhb = Qh + ((size_t)bh * SS + qb) * DKV;
    const short* Qlb = Ql + ((size_t)bh * SS + qb) * DKV;
    const short* Khb = Kh + (size_t)bh * SS * DKV;
    const short* Klb = Kl + (size_t)bh * SS * DKV;
    const short* Vb  = Vt + (size_t)bh * DKV * SS;
    const float* btab = btab_all + h * 4096 + 2048;
    const int* mrow = mask + b * SS;

    int arow = w * 16 + col;
    bf16x8 aqh0 = *(const bf16x8*)(Qhb + arow*64 + quad*8);
    bf16x8 aqh1 = *(const bf16x8*)(Qhb + arow*64 + 32 + quad*8);
    bf16x8 aql0 = *(const bf16x8*)(Qlb + arow*64 + quad*8);
    bf16x8 aql1 = *(const bf16x8*)(Qlb + arow*64 + 32 + quad*8);

    int qg[4];
    const float* btr[4];
    float* arow_out[4];
#pragma unroll
    for (int r = 0; r < 4; ++r) {
        qg[r] = qb + w*16 + quad*4 + r;
        btr[r] = btab - qg[r];
        arow_out[r] = attn_out + ((size_t)bh * SS + qg[r]) * SS;
    }

    float m_r[4], l_r[4];
#pragma unroll
    for (int r = 0; r < 4; ++r) { m_r[r] = -1e30f; l_r[r] = 0.f; }

    // ---- pass 1: per-lane online stats (no cross-lane ops in hot loop) ----
    for (int kt = 0; kt < 32; ++kt) {
        int kb = kt * 64;
        float sv[4][4];
#pragma unroll
        for (int np = 0; np < 2; ++np) {
            const short* Kp0  = Khb + (size_t)(kb + np*32 + col) * 64;
            const short* Kpl0 = Klb + (size_t)(kb + np*32 + col) * 64;
            const short* Kp1  = Kp0  + 16*64;
            const short* Kpl1 = Kpl0 + 16*64;
            bf16x8 kh0a = *(const bf16x8*)(Kp0  + quad*8);
            bf16x8 kh1a = *(const bf16x8*)(Kp0  + 32 + quad*8);
            bf16x8 kl0a = *(const bf16x8*)(Kpl0 + quad*8);
            bf16x8 kl1a = *(const bf16x8*)(Kpl0 + 32 + quad*8);
            bf16x8 kh0b = *(const bf16x8*)(Kp1  + quad*8);
            bf16x8 kh1b = *(const bf16x8*)(Kp1  + 32 + quad*8);
            bf16x8 kl0b = *(const bf16x8*)(Kpl1 + quad*8);
            bf16x8 kl1b = *(const bf16x8*)(Kpl1 + 32 + quad*8);
            f32x4 acc0 = (f32x4){0.f,0.f,0.f,0.f};
            f32x4 acc1 = (f32x4){0.f,0.f,0.f,0.f};
            acc0 = MFMA16(aqh0, kh0a, acc0, 0, 0, 0); acc1 = MFMA16(aqh0, kh0b, acc1, 0, 0, 0);
            acc0 = MFMA16(aqh1, kh1a, acc0, 0, 0, 0); acc1 = MFMA16(aqh1, kh1b, acc1, 0, 0, 0);
            acc0 = MFMA16(aql0, kh0a, acc0, 0, 0, 0); acc1 = MFMA16(aql0, kh0b, acc1, 0, 0, 0);
            acc0 = MFMA16(aql1, kh1a, acc0, 0, 0, 0); acc1 = MFMA16(aql1, kh1b, acc1, 0, 0, 0);
            acc0 = MFMA16(aqh0, kl0a, acc0, 0, 0, 0); acc1 = MFMA16(aqh0, kl0b, acc1, 0, 0, 0);
            acc0 = MFMA16(aqh1, kl1a, acc0, 0, 0, 0); acc1 = MFMA16(aqh1, kl1b, acc1, 0, 0, 0);
            int c0 = kb + np*32 + col;
            int mk0 = mrow[c0], mk1 = mrow[c0 + 16];
#pragma unroll
            for (int r = 0; r < 4; ++r) {
                sv[np*2  ][r] = (mk0 == 0) ? -1e9f : acc0[r] + btr[r][c0];
                sv[np*2+1][r] = (mk1 == 0) ? -1e9f : acc1[r] + btr[r][c0 + 16];
            }
        }
#pragma unroll
        for (int r = 0; r < 4; ++r) {
            float tm = fmaxf(fmaxf(sv[0][r], sv[1][r]), fmaxf(sv[2][r], sv[3][r]));
            float nm = fmaxf(m_r[r], tm);
            l_r[r] = l_r[r] * __expf(m_r[r] - nm)
                   + __expf(sv[0][r]-nm) + __expf(sv[1][r]-nm)
                   + __expf(sv[2][r]-nm) + __expf(sv[3][r]-nm);
            m_r[r] = nm;
        }
    }

    // merge stats across the 16 lanes sharing each row
    float invl[4];
#pragma unroll
    for (int r = 0; r < 4; ++r) {
        float m = m_r[r], l = l_r[r];
#pragma unroll
        for (int d = 1; d < 16; d <<= 1) {
            float mo = __shfl_xor(m, d, 64);
            float lo = __shfl_xor(l, d, 64);
            float nm = fmaxf(m, mo);
            l = l * __expf(m - nm) + lo * __expf(mo - nm);
            m = nm;
        }
        m_r[r] = m;
        invl[r] = 1.0f / l;
    }

    f32x4 O[4];
#pragma unroll
    for (int d = 0; d < 4; ++d) O[d] = (f32x4){0.f,0.f,0.f,0.f};

    // ---- pass 2: recompute, write weights, accumulate P@V (no block sync) ----
    for (int kt = 0; kt < 32; ++kt) {
        int kb = kt * 64;
#pragma unroll
        for (int np = 0; np < 2; ++np) {
            const short* Kp0  = Khb + (size_t)(kb + np*32 + col) * 64;
            const short* Kpl0 = Klb + (size_t)(kb + np*32 + col) * 64;
            const short* Kp1  = Kp0  + 16*64;
            const short* Kpl1 = Kpl0 + 16*64;
            bf16x8 kh0a = *(const bf16x8*)(Kp0  + quad*8);
            bf16x8 kh1a = *(const bf16x8*)(Kp0  + 32 + quad*8);
            bf16x8 kl0a = *(const bf16x8*)(Kpl0 + quad*8);
            bf16x8 kl1a = *(const bf16x8*)(Kpl0 + 32 + quad*8);
            bf16x8 kh0b = *(const bf16x8*)(Kp1  + quad*8);
            bf16x8 kh1b = *(const bf16x8*)(Kp1  + 32 + quad*8);
            bf16x8 kl0b = *(const bf16x8*)(Kpl1 + quad*8);
            bf16x8 kl1b = *(const bf16x8*)(Kpl1 + 32 + quad*8);
            f32x4 acc0 = (f32x4){0.f,0.f,0.f,0.f};
            f32x4 acc1 = (f32x4){0.f,0.f,0.f,0.f};
            acc0 = MFMA16(aqh0, kh0a, acc0, 0, 0, 0); acc1 = MFMA16(aqh0, kh0b, acc1, 0, 0, 0);
            acc0 = MFMA16(aqh1, kh1a, acc0, 0, 0, 0); acc1 = MFMA16(aqh1, kh1b, acc1, 0, 0, 0);
            acc0 = MFMA16(aql0, kh0a, acc0, 0, 0, 0); acc1 = MFMA16(aql0, kh0b, acc1, 0, 0, 0);
            acc0 = MFMA16(aql1, kh1a, acc0, 0, 0, 0); acc1 = MFMA16(aql1, kh1b, acc1, 0, 0, 0);
            acc0 = MFMA16(aqh0, kl0a, acc0, 0, 0, 0); acc1 = MFMA16(aqh0, kl0b, acc1, 0, 0, 0);
            acc0 = MFMA16(aqh1, kl1a, acc0, 0, 0, 0); acc1 = MFMA16(aqh1, kl1b, acc1, 0, 0, 0);
            int c0 = kb + np*32 + col;
            int mk0 = mrow[c0], mk1 = mrow[c0 + 16];
#pragma unroll
            for (int r = 0; r < 4; ++r) {
                float x0 = (mk0 == 0) ? -1e9f : acc0[r] + btr[r][c0];
                float p0 = __expf(x0 - m_r[r]) * invl[r];
                arow_out[r][c0] = p0;
                Pt[w][(quad*4 + r) * 64 + np*32 + col] = f2bf(p0);
                float x1 = (mk1 == 0) ? -1e9f : acc1[r] + btr[r][c0 + 16];
                float p1 = __expf(x1 - m_r[r]) * invl[r];
                arow_out[r][c0 + 16] = p1;
                Pt[w][(quad*4 + r) * 64 + np*32 + 16 + col] = f2bf(p1);
            }
        }
        __threadfence_block();   // wave-private Pt: order DS writes before reads
        bf16x8 ap0 = *(bf16x8*)&Pt[w][col*64 + quad*8];
        bf16x8 ap1 = *(bf16x8*)&Pt[w][col*64 + 32 + quad*8];
#pragma unroll
        for (int dt = 0; dt < 4; ++dt) {
            const short* Vp = Vb + (size_t)(dt*16 + col) * SS + kb;
            bf16x8 bv0 = *(const bf16x8*)(Vp + quad*8);
            bf16x8 bv1 = *(const bf16x8*)(Vp + 32 + quad*8);
            O[dt] = MFMA16(ap0, bv0, O[dt], 0, 0, 0);
            O[dt] = MFMA16(ap1, bv1, O[dt], 0, 0, 0);
        }
    }

    // write context [4096][1024] bf16: row = b*2048+q, col = h*64 + d
#pragma unroll
    for (int dt = 0; dt < 4; ++dt)
#pragma unroll
        for (int r = 0; r < 4; ++r) {
            int row = b * SS + qg[r];
            int cc = h * DKV + dt*16 + col;
            ctx[(size_t)row * DD + cc] = f2bf(O[dt][r]);
        }
}

// ---------------------------------------------------------------------------
extern "C" void kernel_launch(void* const* d_in, const int* in_sizes, int n_in,
                              void* d_out, int out_size, void* d_ws, size_t ws_size,
                              hipStream_t stream)
{
    const float* hidden   = (const float*)d_in[0];
    const int*   mask     = (const int*)d_in[1];
    const float* Wq       = (const float*)d_in[2];
    const float* Wk       = (const float*)d_in[3];
    const float* Wv       = (const float*)d_in[4];
    const float* Wo       = (const float*)d_in[5];
    const float* rel_bias = (const float*)d_in[6];

    float* out  = (float*)d_out;                       // [2,2048,1024]
    float* attn = out + (size_t)BB * SS * DD;          // [2,16,2048,2048]

    char* p = (char*)d_ws;
    auto alloc = [&](size_t bytes) { char* r = p; p += (bytes + 255) & ~(size_t)255; return r; };
    short* Xh    = (short*)alloc((size_t)MROWS * DD * 2);
    short* Xl    = (short*)alloc((size_t)MROWS * DD * 2);
    short* Wqkh  = (short*)alloc((size_t)2048 * DD * 2);
    short* Wqkl  = (short*)alloc((size_t)2048 * DD * 2);
    short* Wvt   = (short*)alloc((size_t)DD * DD * 2);
    short* Wot   = (short*)alloc((size_t)DD * DD * 2);
    short* Qhb   = (short*)alloc((size_t)BH * SS * DKV * 2);
    short* Qlb   = (short*)alloc((size_t)BH * SS * DKV * 2);
    short* Khb   = (short*)alloc((size_t)BH * SS * DKV * 2);
    short* Klb   = (short*)alloc((size_t)BH * SS * DKV * 2);
    short* Vtb   = (short*)alloc((size_t)BH * SS * DKV * 2);
    short* ctx   = (short*)alloc((size_t)MROWS * DD * 2);
    float* btab  = (float*)alloc((size_t)HH * 4096 * 4);

    cast_split_kernel<<<(MROWS * DD / 4 + 255) / 256, 256, 0, stream>>>(hidden, Xh, Xl, MROWS * DD);

    dim3 tb(32, 8), tg(32, 32);
    transpose_split_kernel<<<tg, tb, 0, stream>>>(Wq, Wqkh, Wqkl, 1);
    transpose_split_kernel<<<tg, tb, 0, stream>>>(Wk, Wqkh + (size_t)1024 * DD, Wqkl + (size_t)1024 * DD, 1);
    transpose_split_kernel<<<tg, tb, 0, stream>>>(Wv, Wvt, nullptr, 0);
    transpose_split_kernel<<<tg, tb, 0, stream>>>(Wo, Wot, nullptr, 0);

    bias_table_kernel<<<(HH * 4096) / 256, 256, 0, stream>>>(rel_bias, btab);

    gemm_split_qk_kernel<<<dim3(16, 32), 256, 0, stream>>>(Xh, Xl, Wqkh, Wqkl, Qhb, Qlb, Khb, Klb);

    gemm_plain_kernel<<<dim3(8, 32), 256, 0, stream>>>(Xh, Wvt, Vtb, nullptr, 0);

    attn_kernel<<<dim3(32, 32), 256, 0, stream>>>(Qhb, Qlb, Khb, Klb, Vtb, btab, mask, attn, ctx);

    gemm_plain_kernel<<<dim3(8, 32), 256, 0, stream>>>(ctx, Wot, nullptr, out, 1);
}